// Round 2
// baseline (223.412 us; speedup 1.0000x reference)
//
#include <hip/hip_runtime.h>
#include <hip/hip_fp16.h>

#define Mpts 32768
#define Vv 9
#define Cc 24
#define Hh 120
#define Ww 160
#define Npts (Mpts * 8)          // 262144
#define PIX (Hh * Ww)            // 19200
#define VOXEL 0.04f

// ---------------- workspace layout (bytes) ----------------
// [0,32)    : 3 doubles: sum_z, sum_z2, pos_cnt
// OFF_TF    : tf = transposed feats (V,H,W,C) fp16   : 8294400 B
// OFF_PREH  : pre_h (M,24) f32                        : 3145728 B
// OFF_FEAT  : featbuf (N,24) f32                      : 25165824 B
// OFF_Z     : zbuf (N) f32                            : 1048576 B
#define OFF_TF    32
#define OFF_PREH  (OFF_TF + Vv * PIX * Cc * 2)
#define OFF_FEAT  (OFF_PREH + Mpts * Cc * 4)
#define OFF_Z     (OFF_FEAT + Npts * Cc * 4)

// ---------------- 1) transpose feats (V,C,H,W) f32 -> (V,H,W,C) fp16 -------
__global__ __launch_bounds__(256) void transpose_feats(
    const float* __restrict__ feats, __half* __restrict__ tf) {
  __shared__ float tile[64][Cc + 1];
  int blk = blockIdx.x;               // v*300 + tile
  int v = blk / (PIX / 64);
  int p0 = (blk % (PIX / 64)) * 64;
  const float* src = feats + v * (Cc * PIX);
  for (int i = threadIdx.x; i < Cc * 64; i += 256) {
    int c = i >> 6;
    int p = i & 63;
    tile[p][c] = src[c * PIX + p0 + p];
  }
  __syncthreads();
  unsigned* dst = (unsigned*)(tf + (size_t)v * (PIX * Cc) + (size_t)p0 * Cc);
  for (int i = threadIdx.x; i < Cc * 32; i += 256) {   // 768 uint stores
    int p = i / 12, pr = i - p * 12;
    __half2 hv = __floats2half2_rn(tile[p][2 * pr], tile[p][2 * pr + 1]);
    dst[p * 12 + pr] = *(unsigned*)&hv;
  }
}

// ---------------- 2) pre_h[m,:] = b_sp + pre_feat[m,:] @ W_sp[25:75,:] ------
__global__ __launch_bounds__(256) void pre_h_kernel(
    const float* __restrict__ pre_feat, const float* __restrict__ W_sp,
    const float* __restrict__ b_sp, float* __restrict__ pre_h) {
  __shared__ float Wl[50 * Cc];
  __shared__ float bl[Cc];
  for (int i = threadIdx.x; i < 50 * Cc; i += 256) Wl[i] = W_sp[25 * Cc + i];
  if (threadIdx.x < Cc) bl[threadIdx.x] = b_sp[threadIdx.x];
  __syncthreads();
  int m = blockIdx.x * 256 + threadIdx.x;
  float acc[Cc];
#pragma unroll
  for (int j = 0; j < Cc; j++) acc[j] = bl[j];
  const float* pf = pre_feat + m * 50;
  for (int k = 0; k < 50; k++) {
    float x = pf[k];
#pragma unroll
    for (int j = 0; j < Cc; j++) acc[j] += x * Wl[k * Cc + j];
  }
  float* o = pre_h + m * Cc;
#pragma unroll
  for (int j = 0; j < Cc; j++) o[j] = acc[j];
}

// helper: accumulate 8 fp16 channels from two x-adjacent corners
__device__ __forceinline__ void acc8(uint4 a, uint4 b, float wa, float wb,
                                     float* acc) {
#pragma unroll
  for (int t = 0; t < 4; t++) {
    unsigned ua = ((const unsigned*)&a)[t];
    unsigned ub = ((const unsigned*)&b)[t];
    float2 fa = __half22float2(*(const __half2*)&ua);
    float2 fb = __half22float2(*(const __half2*)&ub);
    acc[2 * t] += wa * fa.x + wb * fb.x;
    acc[2 * t + 1] += wa * fa.y + wb * fb.y;
  }
}

// ---------------- 3) main: project + sample (2 lanes/point) ---------------
__global__ __launch_bounds__(256, 8) void main_kernel(
    const int* __restrict__ pre_coords, const __half* __restrict__ tf,
    const float* __restrict__ KRcam, const float* __restrict__ vol_origin,
    const float* __restrict__ w2ac, float* __restrict__ out,
    float* __restrict__ featbuf, float* __restrict__ zbuf,
    double* __restrict__ red) {
  __shared__ float KR[Vv * 12];
  __shared__ float w2a[12];
  __shared__ float orig[3];
  __shared__ float redl[3][4];
  for (int i = threadIdx.x; i < Vv * 12; i += 256) {
    int v = i / 12, r = i - v * 12;
    KR[i] = KRcam[v * 16 + r];
  }
  if (threadIdx.x < 12) w2a[threadIdx.x] = w2ac[threadIdx.x];
  if (threadIdx.x < 3) orig[threadIdx.x] = vol_origin[threadIdx.x];
  __syncthreads();

  int g = blockIdx.x * 256 + threadIdx.x;   // 2*Npts threads
  int n = g >> 1, row = g & 1;              // row 0 = top, 1 = bottom
  int m = n >> 3, o = n & 7;
  int cx = pre_coords[m * 4 + 1] + ((0xB2 >> o) & 1);
  int cy = pre_coords[m * 4 + 2] + ((0xD4 >> o) & 1);
  int cz = pre_coords[m * 4 + 3] + ((0xE8 >> o) & 1);
  float wx0 = (float)cx * VOXEL + orig[0];
  float wy0 = (float)cy * VOXEL + orig[1];
  float wz0 = (float)cz * VOXEL + orig[2];

  if (row == 0) {   // r_coords
    float camx = w2a[0] * wx0 + w2a[1] * wy0 + w2a[2] * wz0 + w2a[3];
    float camy = w2a[4] * wx0 + w2a[5] * wy0 + w2a[6] * wz0 + w2a[7];
    float camz = w2a[8] * wx0 + w2a[9] * wy0 + w2a[10] * wz0 + w2a[11];
    float4 rc = make_float4(camx, camy, camz, (float)pre_coords[m * 4 + 0]);
    ((float4*)(out + 3 * Npts))[n] = rc;
  }

  float acc[Cc];
#pragma unroll
  for (int c = 0; c < Cc; c++) acc[c] = 0.f;
  float zsum = 0.f;
  int cnt = 0;

  for (int v = 0; v < Vv; v++) {
    const float* kr = &KR[v * 12];
    float ix = kr[0] * wx0 + kr[1] * wy0 + kr[2] * wz0 + kr[3];
    float iy = kr[4] * wx0 + kr[5] * wy0 + kr[6] * wz0 + kr[7];
    float iz = kr[8] * wx0 + kr[9] * wy0 + kr[10] * wz0 + kr[11];
    float sz = (fabsf(iz) > 1e-9f) ? iz : 1e-9f;
    float px = ix / sz;
    float py = iy / sz;
    bool msk = (px >= 0.f) && (px <= (float)(Ww - 1)) && (py >= 0.f) &&
               (py <= (float)(Hh - 1)) && (iz > 0.f);
    if (msk) {
      float fx0 = floorf(px), fy0 = floorf(py);
      float wx = px - fx0, wy = py - fy0;
      int x0 = (int)fx0, y0 = (int)fy0;
      int x1 = min(x0 + 1, Ww - 1);
      int yr = min(y0 + row, Hh - 1);
      float wr = row ? wy : (1.f - wy);
      float wa = wr * (1.f - wx);
      float wb = wr * wx;
      const __half* base = tf + (size_t)v * (PIX * Cc) + (size_t)(yr * Ww) * Cc;
      const uint4* pa = (const uint4*)(base + x0 * Cc);
      const uint4* pb = (const uint4*)(base + x1 * Cc);
      uint4 A0 = pa[0], A1 = pa[1], A2 = pa[2];
      uint4 B0 = pb[0], B1 = pb[1], B2 = pb[2];
      acc8(A0, B0, wa, wb, &acc[0]);
      acc8(A1, B1, wa, wb, &acc[8]);
      acc8(A2, B2, wa, wb, &acc[16]);
      zsum += iz;
      cnt++;
    }
  }

  float denom = fmaxf((float)cnt, 1.f);
  float invd = 1.f / denom;
  float z = zsum * invd;

  // combine top/bottom rows: even lane accumulates odd lane's partial
#pragma unroll
  for (int c = 0; c < Cc; c++) {
    float other = __shfl_down(acc[c], 1);
    acc[c] = (acc[c] + other) * invd;
  }

  if (row == 0) {
    float4* fb = (float4*)(featbuf + (size_t)n * Cc);
#pragma unroll
    for (int q = 0; q < 6; q++)
      fb[q] = make_float4(acc[4 * q], acc[4 * q + 1], acc[4 * q + 2],
                          acc[4 * q + 3]);
    zbuf[n] = z;
    out[2 * Npts + n] = (float)cnt;
  }

  // reduction for zmean / znorm (even lanes only contribute)
  bool pos = (row == 0) && (z > 0.f);
  float rz = pos ? z : 0.f;
  float rz2 = rz * rz;
  float rcn = pos ? 1.f : 0.f;
#pragma unroll
  for (int off = 32; off > 0; off >>= 1) {
    rz += __shfl_down(rz, off);
    rz2 += __shfl_down(rz2, off);
    rcn += __shfl_down(rcn, off);
  }
  int wid = threadIdx.x >> 6, lid = threadIdx.x & 63;
  if (lid == 0) {
    redl[0][wid] = rz;
    redl[1][wid] = rz2;
    redl[2][wid] = rcn;
  }
  __syncthreads();
  if (threadIdx.x == 0) {
    float a = 0.f, b = 0.f, c = 0.f;
#pragma unroll
    for (int w = 0; w < 4; w++) {
      a += redl[0][w];
      b += redl[1][w];
      c += redl[2][w];
    }
    atomicAdd(&red[0], (double)a);
    atomicAdd(&red[1], (double)b);
    atomicAdd(&red[2], (double)c);
  }
}

// ---------------- 4) finalize: zn + h-matmul + relu + heads ----------------
__global__ __launch_bounds__(256) void final_kernel(
    const float* __restrict__ zbuf, const float* __restrict__ featbuf,
    const float* __restrict__ pre_h, const float* __restrict__ W_sp,
    const float* __restrict__ W_t, const float* __restrict__ b_t,
    const float* __restrict__ W_o, const float* __restrict__ b_o,
    const double* __restrict__ red, float* __restrict__ out) {
  __shared__ float Wl[25 * Cc];     // W_sp rows 0..24 (feat 24 + zn)
  __shared__ float wt[Cc], wo[Cc];
  __shared__ float bt, bo, s_zmean, s_izn;
  for (int i = threadIdx.x; i < 25 * Cc; i += 256) Wl[i] = W_sp[i];
  if (threadIdx.x < Cc) {
    wt[threadIdx.x] = W_t[threadIdx.x];
    wo[threadIdx.x] = W_o[threadIdx.x];
  }
  if (threadIdx.x == 0) {
    bt = b_t[0];
    bo = b_o[0];
    double sz = red[0], sz2 = red[1], cd = red[2];
    double npos = (cd > 0.0) ? cd : 1.0;
    double zmean = sz / npos;
    double var = sz2 - 2.0 * zmean * sz + cd * zmean * zmean;
    if (var < 0.0) var = 0.0;
    double znorm = sqrt(var) + 1e-5;
    s_zmean = (float)zmean;
    s_izn = (float)(1.0 / znorm);
  }
  __syncthreads();
  int n = blockIdx.x * 256 + threadIdx.x;
  int m = n >> 3;
  float z = zbuf[n];
  float zn = (z > 0.f) ? (z - s_zmean) * s_izn : 0.f;

  float feat[Cc];
  const float4* fb = (const float4*)(featbuf + (size_t)n * Cc);
#pragma unroll
  for (int q = 0; q < 6; q++) {
    float4 f = fb[q];
    feat[4 * q] = f.x;
    feat[4 * q + 1] = f.y;
    feat[4 * q + 2] = f.z;
    feat[4 * q + 3] = f.w;
  }

  float h[Cc];
  const float* ph = pre_h + m * Cc;
#pragma unroll
  for (int j = 0; j < Cc; j++) h[j] = ph[j] + zn * Wl[24 * Cc + j];
  for (int c = 0; c < Cc; c++) {
    float f = feat[c];
#pragma unroll
    for (int j = 0; j < Cc; j++) h[j] += f * Wl[c * Cc + j];
  }
  float tsdf = bt, occ = bo;
#pragma unroll
  for (int j = 0; j < Cc; j++) {
    float hr = fmaxf(h[j], 0.f);
    tsdf += hr * wt[j];
    occ += hr * wo[j];
  }
  ((float2*)out)[n] = make_float2(tsdf, occ);
}

// ---------------- launch ---------------------------------------------------
extern "C" void kernel_launch(void* const* d_in, const int* in_sizes, int n_in,
                              void* d_out, int out_size, void* d_ws,
                              size_t ws_size, hipStream_t stream) {
  const float* pre_feat = (const float*)d_in[0];
  const int* pre_coords = (const int*)d_in[1];
  const float* feats = (const float*)d_in[2];
  const float* KRcam = (const float*)d_in[3];
  const float* vol_origin = (const float*)d_in[4];
  const float* w2ac = (const float*)d_in[5];
  const float* W_sp = (const float*)d_in[6];
  const float* b_sp = (const float*)d_in[7];
  const float* W_t = (const float*)d_in[8];
  const float* b_t = (const float*)d_in[9];
  const float* W_o = (const float*)d_in[10];
  const float* b_o = (const float*)d_in[11];

  float* out = (float*)d_out;
  char* ws = (char*)d_ws;
  double* red = (double*)ws;
  __half* tf = (__half*)(ws + OFF_TF);
  float* pre_h = (float*)(ws + OFF_PREH);
  float* featbuf = (float*)(ws + OFF_FEAT);
  float* zbuf = (float*)(ws + OFF_Z);

  hipMemsetAsync(red, 0, 32, stream);

  transpose_feats<<<Vv * (PIX / 64), 256, 0, stream>>>(feats, tf);
  pre_h_kernel<<<Mpts / 256, 256, 0, stream>>>(pre_feat, W_sp, b_sp, pre_h);
  main_kernel<<<2 * Npts / 256, 256, 0, stream>>>(pre_coords, tf, KRcam,
                                                  vol_origin, w2ac, out,
                                                  featbuf, zbuf, red);
  final_kernel<<<Npts / 256, 256, 0, stream>>>(zbuf, featbuf, pre_h, W_sp, W_t,
                                               b_t, W_o, b_o, red, out);
}

// Round 3
// 166.975 us; speedup vs baseline: 1.3380x; 1.3380x over previous
//
#include <hip/hip_runtime.h>
#include <hip/hip_fp16.h>

#define Mpts 32768
#define Vv 9
#define Cc 24
#define Hh 120
#define Ww 160
#define Npts (Mpts * 8)          // 262144
#define PIX (Hh * Ww)            // 19200
#define VOXEL 0.04f

// ---------------- workspace layout (bytes) ----------------
// [0,64)    : 3 doubles: sum_z, sum_z2, pos_cnt (zeroed by prep)
// OFF_TF    : tf = transposed feats (V,H,W,C) fp16 : 8294400 B
// OFF_PREH  : pre_h (M,24) f32                      : 3145728 B
// OFF_HP    : hp (12,N) uint (= half2 channel pairs): 12582912 B
// OFF_Z     : zbuf (N) f32                          : 1048576 B
#define OFF_TF    64
#define OFF_PREH  (OFF_TF + Vv * PIX * Cc * 2)
#define OFF_HP    (OFF_PREH + Mpts * Cc * 4)
#define OFF_Z     (OFF_HP + Npts * Cc * 2)

__device__ __forceinline__ unsigned pack2(float a, float b) {
  __half2 h = __floats2half2_rn(a, b);
  return *(unsigned*)&h;
}

// ---------------- 1) prep: transpose feats -> fp16 (V,H,W,C), pre_h, zero red
__global__ __launch_bounds__(256) void prep_kernel(
    const float* __restrict__ feats, const float* __restrict__ pre_feat,
    const float* __restrict__ W_sp, const float* __restrict__ b_sp,
    __half* __restrict__ tf, float* __restrict__ pre_h,
    double* __restrict__ red) {
  __shared__ float tile[64][Cc + 1];
  __shared__ float Wl[50 * Cc];
  __shared__ float bl[Cc];
  int blk = blockIdx.x;
  if (blk == 0 && threadIdx.x < 3) red[threadIdx.x] = 0.0;

  if (blk < Vv * 300) {
    // ---- transpose part: one block = one view x 64-pixel strip ----
    int v = blk / 300;
    int p0 = (blk % 300) * 64;
    const float* src = feats + (size_t)v * (Cc * PIX);
    for (int i = threadIdx.x; i < Cc * 64; i += 256) {
      int c = i >> 6, p = i & 63;
      tile[p][c] = src[c * PIX + p0 + p];
    }
    __syncthreads();
    uint4* dst = (uint4*)(tf + ((size_t)v * PIX + p0) * Cc);
    if (threadIdx.x < 192) {
      int i = threadIdx.x;
      int p = i / 3, r = i - p * 3;       // 8-channel group r of pixel p
      const float* t = &tile[p][r * 8];
      uint4 u;
      u.x = pack2(t[0], t[1]);
      u.y = pack2(t[2], t[3]);
      u.z = pack2(t[4], t[5]);
      u.w = pack2(t[6], t[7]);
      dst[p * 3 + r] = u;
    }
  } else {
    // ---- pre_h part: pre_h[m,:] = b_sp + pre_feat[m,:] @ W_sp[25:75,:] ----
    int mb = blk - Vv * 300;
    for (int i = threadIdx.x; i < 50 * Cc; i += 256) Wl[i] = W_sp[25 * Cc + i];
    if (threadIdx.x < Cc) bl[threadIdx.x] = b_sp[threadIdx.x];
    __syncthreads();
    int m = mb * 256 + threadIdx.x;
    float acc[Cc];
#pragma unroll
    for (int j = 0; j < Cc; j++) acc[j] = bl[j];
    const float* pf = pre_feat + (size_t)m * 50;
    for (int k = 0; k < 50; k++) {
      float x = pf[k];
#pragma unroll
      for (int j = 0; j < Cc; j++) acc[j] += x * Wl[k * Cc + j];
    }
    float* o = pre_h + (size_t)m * Cc;
#pragma unroll
    for (int j = 0; j < Cc; j++) o[j] = acc[j];
  }
}

// helper: acc[0..7] += wa * half2x4(a) + wb * half2x4(b)
__device__ __forceinline__ void acc8(uint4 a, uint4 b, float wa, float wb,
                                     float* acc) {
#pragma unroll
  for (int t = 0; t < 4; t++) {
    unsigned ua = ((const unsigned*)&a)[t];
    unsigned ub = ((const unsigned*)&b)[t];
    float2 fa = __half22float2(*(const __half2*)&ua);
    float2 fb = __half22float2(*(const __half2*)&ub);
    acc[2 * t] += wa * fa.x + wb * fb.x;
    acc[2 * t + 1] += wa * fa.y + wb * fb.y;
  }
}

// ---------------- 2) main: project + sample + h-partial + reduction --------
__global__ __launch_bounds__(256) void main_kernel(
    const int* __restrict__ pre_coords, const uint4* __restrict__ tfq,
    const float* __restrict__ KRcam, const float* __restrict__ vol_origin,
    const float* __restrict__ w2ac, const float* __restrict__ W_sp,
    const float* __restrict__ pre_h, float* __restrict__ out,
    unsigned* __restrict__ hp, float* __restrict__ zbuf,
    double* __restrict__ red) {
  __shared__ float KR[Vv * 12];
  __shared__ float Wl[Cc * Cc];      // W_sp[0:24,:]
  __shared__ float w2a[12];
  __shared__ float orig[3];
  __shared__ float redl[3][4];
  for (int i = threadIdx.x; i < Vv * 12; i += 256) {
    int v = i / 12, r = i - v * 12;
    KR[i] = KRcam[v * 16 + r];
  }
  for (int i = threadIdx.x; i < Cc * Cc; i += 256) Wl[i] = W_sp[i];
  if (threadIdx.x < 12) w2a[threadIdx.x] = w2ac[threadIdx.x];
  if (threadIdx.x < 3) orig[threadIdx.x] = vol_origin[threadIdx.x];
  __syncthreads();

  int n = blockIdx.x * 256 + threadIdx.x;
  int m = n >> 3, o = n & 7;
  int cx = pre_coords[m * 4 + 1] + ((0xB2 >> o) & 1);
  int cy = pre_coords[m * 4 + 2] + ((0xD4 >> o) & 1);
  int cz = pre_coords[m * 4 + 3] + ((0xE8 >> o) & 1);
  float wx0 = (float)cx * VOXEL + orig[0];
  float wy0 = (float)cy * VOXEL + orig[1];
  float wz0 = (float)cz * VOXEL + orig[2];

  {  // r_coords
    float camx = w2a[0] * wx0 + w2a[1] * wy0 + w2a[2] * wz0 + w2a[3];
    float camy = w2a[4] * wx0 + w2a[5] * wy0 + w2a[6] * wz0 + w2a[7];
    float camz = w2a[8] * wx0 + w2a[9] * wy0 + w2a[10] * wz0 + w2a[11];
    float4 rc = make_float4(camx, camy, camz, (float)pre_coords[m * 4 + 0]);
    ((float4*)(out + 3 * Npts))[n] = rc;
  }

  float acc[Cc];
#pragma unroll
  for (int c = 0; c < Cc; c++) acc[c] = 0.f;
  float zsum = 0.f;
  int cnt = 0;

  for (int v = 0; v < Vv; v++) {
    const float* kr = &KR[v * 12];
    float ix = kr[0] * wx0 + kr[1] * wy0 + kr[2] * wz0 + kr[3];
    float iy = kr[4] * wx0 + kr[5] * wy0 + kr[6] * wz0 + kr[7];
    float iz = kr[8] * wx0 + kr[9] * wy0 + kr[10] * wz0 + kr[11];
    float sz = (fabsf(iz) > 1e-9f) ? iz : 1e-9f;
    float px = ix / sz;
    float py = iy / sz;
    bool msk = (px >= 0.f) && (px <= (float)(Ww - 1)) && (py >= 0.f) &&
               (py <= (float)(Hh - 1)) && (iz > 0.f);
    if (msk) {
      int x0 = (int)floorf(px), y0 = (int)floorf(py);
      int xs = min(x0, Ww - 2), ys = min(y0, Hh - 2);
      float wx = px - (float)xs, wy = py - (float)ys;
      float w00 = (1.f - wx) * (1.f - wy);
      float w10 = wx * (1.f - wy);
      float w01 = (1.f - wx) * wy;
      float w11 = wx * wy;
      // contiguous 96B span: pixels (ys,xs),(ys,xs+1); next row +Ww pixels
      const uint4* p = tfq + ((size_t)v * PIX + ys * Ww + xs) * 3;
      const uint4* q = p + Ww * 3;
      uint4 A0 = p[0], A1 = p[1], A2 = p[2];
      uint4 B0 = p[3], B1 = p[4], B2 = p[5];
      uint4 C0 = q[0], C1 = q[1], C2 = q[2];
      uint4 D0 = q[3], D1 = q[4], D2 = q[5];
      acc8(A0, B0, w00, w10, &acc[0]);
      acc8(A1, B1, w00, w10, &acc[8]);
      acc8(A2, B2, w00, w10, &acc[16]);
      acc8(C0, D0, w01, w11, &acc[0]);
      acc8(C1, D1, w01, w11, &acc[8]);
      acc8(C2, D2, w01, w11, &acc[16]);
      zsum += iz;
      cnt++;
    }
  }

  float denom = fmaxf((float)cnt, 1.f);
  float invd = 1.f / denom;
  float z = zsum * invd;

  // h = pre_h[m] + (acc*invd) @ W_sp[0:24,:]
  float h[Cc];
  const float* ph = pre_h + (size_t)m * Cc;
#pragma unroll
  for (int j = 0; j < Cc; j++) h[j] = ph[j];
  for (int c = 0; c < Cc; c++) {
    float f = acc[c] * invd;
#pragma unroll
    for (int j = 0; j < Cc; j++) h[j] += f * Wl[c * Cc + j];
  }
#pragma unroll
  for (int j2 = 0; j2 < 12; j2++)
    hp[(size_t)j2 * Npts + n] = pack2(h[2 * j2], h[2 * j2 + 1]);

  zbuf[n] = z;
  out[2 * Npts + n] = (float)cnt;

  // reduction for zmean / znorm
  float rz = (z > 0.f) ? z : 0.f;
  float rz2 = rz * rz;
  float rcn = (z > 0.f) ? 1.f : 0.f;
#pragma unroll
  for (int off = 32; off > 0; off >>= 1) {
    rz += __shfl_down(rz, off);
    rz2 += __shfl_down(rz2, off);
    rcn += __shfl_down(rcn, off);
  }
  int wid = threadIdx.x >> 6, lid = threadIdx.x & 63;
  if (lid == 0) {
    redl[0][wid] = rz;
    redl[1][wid] = rz2;
    redl[2][wid] = rcn;
  }
  __syncthreads();
  if (threadIdx.x == 0) {
    float a = 0.f, b = 0.f, c = 0.f;
#pragma unroll
    for (int w = 0; w < 4; w++) {
      a += redl[0][w];
      b += redl[1][w];
      c += redl[2][w];
    }
    atomicAdd(&red[0], (double)a);
    atomicAdd(&red[1], (double)b);
    atomicAdd(&red[2], (double)c);
  }
}

// ---------------- 3) finalize: zn + relu + heads ---------------------------
__global__ __launch_bounds__(256) void final_kernel(
    const float* __restrict__ zbuf, const unsigned* __restrict__ hp,
    const float* __restrict__ W_sp, const float* __restrict__ W_t,
    const float* __restrict__ b_t, const float* __restrict__ W_o,
    const float* __restrict__ b_o, const double* __restrict__ red,
    float* __restrict__ out) {
  __shared__ float wz[Cc], wt[Cc], wo[Cc];
  __shared__ float bt, bo, s_zmean, s_izn;
  if (threadIdx.x < Cc) {
    wz[threadIdx.x] = W_sp[24 * Cc + threadIdx.x];
    wt[threadIdx.x] = W_t[threadIdx.x];
    wo[threadIdx.x] = W_o[threadIdx.x];
  }
  if (threadIdx.x == 0) {
    bt = b_t[0];
    bo = b_o[0];
    double sz = red[0], sz2 = red[1], cd = red[2];
    double npos = (cd > 0.0) ? cd : 1.0;
    double zmean = sz / npos;
    double var = sz2 - 2.0 * zmean * sz + cd * zmean * zmean;
    if (var < 0.0) var = 0.0;
    double znorm = sqrt(var) + 1e-5;
    s_zmean = (float)zmean;
    s_izn = (float)(1.0 / znorm);
  }
  __syncthreads();
  int n = blockIdx.x * 256 + threadIdx.x;
  float z = zbuf[n];
  float zn = (z > 0.f) ? (z - s_zmean) * s_izn : 0.f;
  float tsdf = bt, occ = bo;
#pragma unroll
  for (int j2 = 0; j2 < 12; j2++) {
    unsigned u = hp[(size_t)j2 * Npts + n];
    float2 f = __half22float2(*(const __half2*)&u);
    float h0 = fmaxf(f.x + zn * wz[2 * j2], 0.f);
    float h1 = fmaxf(f.y + zn * wz[2 * j2 + 1], 0.f);
    tsdf += h0 * wt[2 * j2] + h1 * wt[2 * j2 + 1];
    occ += h0 * wo[2 * j2] + h1 * wo[2 * j2 + 1];
  }
  ((float2*)out)[n] = make_float2(tsdf, occ);
}

// ---------------- launch ---------------------------------------------------
extern "C" void kernel_launch(void* const* d_in, const int* in_sizes, int n_in,
                              void* d_out, int out_size, void* d_ws,
                              size_t ws_size, hipStream_t stream) {
  const float* pre_feat = (const float*)d_in[0];
  const int* pre_coords = (const int*)d_in[1];
  const float* feats = (const float*)d_in[2];
  const float* KRcam = (const float*)d_in[3];
  const float* vol_origin = (const float*)d_in[4];
  const float* w2ac = (const float*)d_in[5];
  const float* W_sp = (const float*)d_in[6];
  const float* b_sp = (const float*)d_in[7];
  const float* W_t = (const float*)d_in[8];
  const float* b_t = (const float*)d_in[9];
  const float* W_o = (const float*)d_in[10];
  const float* b_o = (const float*)d_in[11];

  float* out = (float*)d_out;
  char* ws = (char*)d_ws;
  double* red = (double*)ws;
  __half* tf = (__half*)(ws + OFF_TF);
  float* pre_h = (float*)(ws + OFF_PREH);
  unsigned* hp = (unsigned*)(ws + OFF_HP);
  float* zbuf = (float*)(ws + OFF_Z);

  prep_kernel<<<Vv * 300 + Mpts / 256, 256, 0, stream>>>(feats, pre_feat, W_sp,
                                                         b_sp, tf, pre_h, red);
  main_kernel<<<Npts / 256, 256, 0, stream>>>(pre_coords, (const uint4*)tf,
                                              KRcam, vol_origin, w2ac, W_sp,
                                              pre_h, out, hp, zbuf, red);
  final_kernel<<<Npts / 256, 256, 0, stream>>>(zbuf, hp, W_sp, W_t, b_t, W_o,
                                               b_o, red, out);
}